// Round 1
// baseline (208.517 us; speedup 1.0000x reference)
//
#include <hip/hip_runtime.h>
#include <math.h>

// ws layout (floats):
// 0:H1[1024] 1024:D1 2048:Svec 3072:Cvec 4096:Avec 5120:Z[3072]
// 8192:Uacc[1024] 9216:Vacc[1024] 16384:S[1024*1024]

__global__ __launch_bounds__(256) void k_zero(float* a, float* b) {
    int i = blockIdx.x * 256 + threadIdx.x;  // grid 8 -> 2048
    a[i] = 0.f;
    b[i] = 0.f;
}

__global__ __launch_bounds__(256) void k_build_z(const float* __restrict__ x,
                                                 const float* __restrict__ q,
                                                 const float* __restrict__ p,
                                                 float* __restrict__ Z) {
    int j = blockIdx.x * 256 + threadIdx.x;  // grid 12 -> 3072
    float v = (j < 1024) ? x[j] : (j < 2048 ? q[j - 1024] : p[j - 2048]);
    Z[j] = v;
}

// Uacc[k] += sum_{j in chunk} Z[j] * W1[j,k]   (coalesced over k)
__global__ __launch_bounds__(256) void k_u_partial(const float* __restrict__ W1,
                                                   const float* __restrict__ Z,
                                                   float* __restrict__ Uacc) {
    int k = blockIdx.x * 256 + threadIdx.x;   // grid (4, 48)
    int j0 = blockIdx.y * 64;
    __shared__ float zs[64];
    if (threadIdx.x < 64) zs[threadIdx.x] = Z[j0 + threadIdx.x];
    __syncthreads();
    float acc = 0.f;
#pragma unroll 8
    for (int j = 0; j < 64; ++j) acc += zs[j] * W1[(j0 + j) * 1024 + k];
    atomicAdd(&Uacc[k], acc);
}

__global__ __launch_bounds__(256) void k_h1(const float* __restrict__ Uacc,
                                            const float* __restrict__ b1,
                                            float* __restrict__ H1, float* __restrict__ D1) {
    int k = blockIdx.x * 256 + threadIdx.x;  // grid 4
    float h = tanhf(Uacc[k] + b1[k]);
    H1[k] = h;
    D1[k] = 1.f - h * h;
}

// Vacc[m] += sum_{k in chunk} H1[k] * W2[k,m]
__global__ __launch_bounds__(256) void k_v_partial(const float* __restrict__ W2,
                                                   const float* __restrict__ H1,
                                                   float* __restrict__ Vacc) {
    int m = blockIdx.x * 256 + threadIdx.x;   // grid (4, 16)
    int k0 = blockIdx.y * 64;
    __shared__ float hs[64];
    if (threadIdx.x < 64) hs[threadIdx.x] = H1[k0 + threadIdx.x];
    __syncthreads();
    float acc = 0.f;
#pragma unroll 8
    for (int k = 0; k < 64; ++k) acc += hs[k] * W2[(k0 + k) * 1024 + m];
    atomicAdd(&Vacc[m], acc);
}

__global__ __launch_bounds__(256) void k_h2(const float* __restrict__ Vacc,
                                            const float* __restrict__ b2,
                                            const float* __restrict__ W3,
                                            float* __restrict__ Svec, float* __restrict__ Cvec) {
    int m = blockIdx.x * 256 + threadIdx.x;  // grid 4
    float h = tanhf(Vacc[m] + b2[m]);
    float d2 = 1.f - h * h;
    float w3 = W3[m];
    Svec[m] = d2 * w3;
    Cvec[m] = -2.f * h * d2 * w3;
}

// a[k] = -2*h1[k]*d1[k]*(sum_m W2[k,m]*s[m])
__global__ __launch_bounds__(256) void k_g(const float* __restrict__ W2,
                                           const float* __restrict__ Svec,
                                           const float* __restrict__ H1,
                                           const float* __restrict__ D1,
                                           float* __restrict__ Avec) {
    int k = blockIdx.x;  // grid 1024
    int t = threadIdx.x;
    float acc = 0.f;
#pragma unroll
    for (int m = t; m < 1024; m += 256) acc += W2[k * 1024 + m] * Svec[m];
    for (int o = 32; o; o >>= 1) acc += __shfl_down(acc, o);
    __shared__ float red[4];
    int lane = t & 63, w = t >> 6;
    if (lane == 0) red[w] = acc;
    __syncthreads();
    if (t == 0) {
        float g = red[0] + red[1] + red[2] + red[3];
        Avec[k] = -2.f * H1[k] * D1[k] * g;
    }
}

// S[i,m] = c[m] * sum_k (W1[i,k]*d1[k]) * W2[k,m]
__global__ __launch_bounds__(256) void k_gemm1(const float* __restrict__ W1,
                                               const float* __restrict__ W2,
                                               const float* __restrict__ D1,
                                               const float* __restrict__ Cvec,
                                               float* __restrict__ S) {
    __shared__ float As[16][68];  // As[kk][i]
    __shared__ float Bs[16][68];  // Bs[kk][m] = W2[k,m]*d1[k]
    int i0 = blockIdx.y * 64, m0 = blockIdx.x * 64;
    int tid = threadIdx.x, tx = tid & 15, ty = tid >> 4;
    float acc[4][4] = {};
    for (int k0 = 0; k0 < 1024; k0 += 16) {
        int li = tid >> 2, lk = (tid & 3) << 2;
        float4 a4 = *(const float4*)(W1 + (i0 + li) * 1024 + k0 + lk);
        As[lk + 0][li] = a4.x; As[lk + 1][li] = a4.y;
        As[lk + 2][li] = a4.z; As[lk + 3][li] = a4.w;
        int lkk = tid >> 4, lm = (tid & 15) << 2;
        float4 b4 = *(const float4*)(W2 + (k0 + lkk) * 1024 + m0 + lm);
        float dd = D1[k0 + lkk];
        *(float4*)&Bs[lkk][lm] = make_float4(b4.x * dd, b4.y * dd, b4.z * dd, b4.w * dd);
        __syncthreads();
#pragma unroll
        for (int kk = 0; kk < 16; ++kk) {
            float4 a = *(const float4*)&As[kk][ty * 4];
            float4 b = *(const float4*)&Bs[kk][tx * 4];
            float av[4] = {a.x, a.y, a.z, a.w};
            float bv[4] = {b.x, b.y, b.z, b.w};
#pragma unroll
            for (int r = 0; r < 4; ++r)
#pragma unroll
                for (int c = 0; c < 4; ++c) acc[r][c] += av[r] * bv[c];
        }
        __syncthreads();
    }
#pragma unroll
    for (int r = 0; r < 4; ++r) {
        int i = i0 + ty * 4 + r;
#pragma unroll
        for (int c = 0; c < 4; ++c) {
            int m = m0 + tx * 4 + c;
            S[i * 1024 + m] = acc[r][c] * Cvec[m];
        }
    }
}

// Wm[i,k] = sum_m S[i,m]*W2[k,m]; DR = a[k]*W1[i,k] + d1[k]*Wm;
// out[i] += C[i,:]·DR ; out[1024+i] -= B[i,:]·DR
__global__ __launch_bounds__(256) void k_gemm2(const float* __restrict__ S,
                                               const float* __restrict__ W2,
                                               const float* __restrict__ W1,
                                               const float* __restrict__ D1,
                                               const float* __restrict__ Avec,
                                               float* __restrict__ out) {
    __shared__ float As[16][68];  // As[mm][i]
    __shared__ float Bs[16][68];  // Bs[mm][kk] = W2[k0g+kk, m0+mm]
    int i0 = blockIdx.y * 64, k0g = blockIdx.x * 64;
    int tid = threadIdx.x, tx = tid & 15, ty = tid >> 4;
    float acc[4][4] = {};
    for (int m0 = 0; m0 < 1024; m0 += 16) {
        int li = tid >> 2, lm = (tid & 3) << 2;
        float4 a4 = *(const float4*)(S + (i0 + li) * 1024 + m0 + lm);
        As[lm + 0][li] = a4.x; As[lm + 1][li] = a4.y;
        As[lm + 2][li] = a4.z; As[lm + 3][li] = a4.w;
        int lkk = tid >> 2, lm2 = (tid & 3) << 2;
        float4 b4 = *(const float4*)(W2 + (k0g + lkk) * 1024 + m0 + lm2);
        Bs[lm2 + 0][lkk] = b4.x; Bs[lm2 + 1][lkk] = b4.y;
        Bs[lm2 + 2][lkk] = b4.z; Bs[lm2 + 3][lkk] = b4.w;
        __syncthreads();
#pragma unroll
        for (int mm = 0; mm < 16; ++mm) {
            float4 a = *(const float4*)&As[mm][ty * 4];
            float4 b = *(const float4*)&Bs[mm][tx * 4];
            float av[4] = {a.x, a.y, a.z, a.w};
            float bv[4] = {b.x, b.y, b.z, b.w};
#pragma unroll
            for (int r = 0; r < 4; ++r)
#pragma unroll
                for (int c = 0; c < 4; ++c) acc[r][c] += av[r] * bv[c];
        }
        __syncthreads();
    }
    float pq[4] = {0, 0, 0, 0}, pp[4] = {0, 0, 0, 0};
#pragma unroll
    for (int r = 0; r < 4; ++r) {
        int i = i0 + ty * 4 + r;
        int kb = k0g + tx * 4;
        float4 wa = *(const float4*)(W1 + i * 1024 + kb);
        float4 wb = *(const float4*)(W1 + (1024 + i) * 1024 + kb);
        float4 wc = *(const float4*)(W1 + (2048 + i) * 1024 + kb);
        float4 d1v = *(const float4*)(D1 + kb);
        float4 av = *(const float4*)(Avec + kb);
        float dr0 = av.x * wa.x + d1v.x * acc[r][0];
        float dr1 = av.y * wa.y + d1v.y * acc[r][1];
        float dr2 = av.z * wa.z + d1v.z * acc[r][2];
        float dr3 = av.w * wa.w + d1v.w * acc[r][3];
        pq[r] = wb.x * dr0 + wb.y * dr1 + wb.z * dr2 + wb.w * dr3;
        pp[r] = wc.x * dr0 + wc.y * dr1 + wc.z * dr2 + wc.w * dr3;
    }
#pragma unroll
    for (int r = 0; r < 4; ++r) {
        for (int o = 8; o; o >>= 1) {
            pq[r] += __shfl_xor(pq[r], o);
            pp[r] += __shfl_xor(pp[r], o);
        }
    }
    if (tx == 0) {
#pragma unroll
        for (int r = 0; r < 4; ++r) {
            int i = i0 + ty * 4 + r;
            atomicAdd(&out[i], pp[r]);
            atomicAdd(&out[1024 + i], -pq[r]);
        }
    }
}

extern "C" void kernel_launch(void* const* d_in, const int* in_sizes, int n_in,
                              void* d_out, int out_size, void* d_ws, size_t ws_size,
                              hipStream_t stream) {
    const float* x = (const float*)d_in[0];
    const float* q = (const float*)d_in[1];
    const float* p = (const float*)d_in[2];
    const float* W1 = (const float*)d_in[3];
    const float* b1 = (const float*)d_in[4];
    const float* W2 = (const float*)d_in[5];
    const float* b2 = (const float*)d_in[6];
    const float* W3 = (const float*)d_in[7];
    float* out = (float*)d_out;
    float* ws = (float*)d_ws;
    float* H1 = ws, *D1 = ws + 1024, *Svec = ws + 2048, *Cvec = ws + 3072;
    float* Avec = ws + 4096, *Z = ws + 5120, *Uacc = ws + 8192;
    float* S = ws + 16384;

    k_zero<<<8, 256, 0, stream>>>(Uacc, out);                       // zero Uacc+Vacc (2048) and out (2048)
    k_build_z<<<12, 256, 0, stream>>>(x, q, p, Z);
    k_u_partial<<<dim3(4, 48), 256, 0, stream>>>(W1, Z, Uacc);
    k_h1<<<4, 256, 0, stream>>>(Uacc, b1, H1, D1);
    k_v_partial<<<dim3(4, 16), 256, 0, stream>>>(W2, H1, Uacc + 1024);
    k_h2<<<4, 256, 0, stream>>>(Uacc + 1024, b2, W3, Svec, Cvec);
    k_g<<<1024, 256, 0, stream>>>(W2, Svec, H1, D1, Avec);
    k_gemm1<<<dim3(16, 16), 256, 0, stream>>>(W1, W2, D1, Cvec, S);
    k_gemm2<<<dim3(16, 16), 256, 0, stream>>>(S, W2, W1, D1, Avec, out);
}

// Round 2
// 144.831 us; speedup vs baseline: 1.4397x; 1.4397x over previous
//
#include <hip/hip_runtime.h>
#include <math.h>

typedef unsigned short u16;
typedef __bf16 bf16x8 __attribute__((ext_vector_type(8)));
typedef float f32x4 __attribute__((ext_vector_type(4)));

// ---------- helpers ----------
__device__ inline u16 bf16_rn(float x) {
    unsigned u = __float_as_uint(x);
    return (u16)((u + 0x7FFFu + ((u >> 16) & 1u)) >> 16);
}
__device__ inline void split2(float x, u16& h, u16& l) {
    h = bf16_rn(x);
    float hf = __uint_as_float(((unsigned)h) << 16);
    l = bf16_rn(x - hf);
}
__device__ inline uint2 pack4(u16 a, u16 b, u16 c, u16 d) {
    uint2 r;
    r.x = (unsigned)a | ((unsigned)b << 16);
    r.y = (unsigned)c | ((unsigned)d << 16);
    return r;
}
__device__ inline f32x4 mfma16(bf16x8 a, bf16x8 b, f32x4 c) {
    return __builtin_amdgcn_mfma_f32_16x16x32_bf16(a, b, c, 0, 0, 0);
}

// ---------- small fp32 kernels (verified round 1) ----------
// init: build Z, zero out[2048] and Uacc/Vacc[2048]
__global__ __launch_bounds__(256) void k_init(const float* __restrict__ x,
                                              const float* __restrict__ q,
                                              const float* __restrict__ p,
                                              float* __restrict__ Z,
                                              float* __restrict__ out,
                                              float* __restrict__ uv) {
    int j = blockIdx.x * 256 + threadIdx.x;  // grid 12 -> 3072
    if (j < 2048) { out[j] = 0.f; uv[j] = 0.f; }
    Z[j] = (j < 1024) ? x[j] : (j < 2048 ? q[j - 1024] : p[j - 2048]);
}

__global__ __launch_bounds__(256) void k_u_partial(const float* __restrict__ W1,
                                                   const float* __restrict__ Z,
                                                   float* __restrict__ Uacc) {
    int k = blockIdx.x * 256 + threadIdx.x;  // grid (4,48)
    int j0 = blockIdx.y * 64;
    __shared__ float zs[64];
    if (threadIdx.x < 64) zs[threadIdx.x] = Z[j0 + threadIdx.x];
    __syncthreads();
    float acc = 0.f;
#pragma unroll 8
    for (int j = 0; j < 64; ++j) acc += zs[j] * W1[(j0 + j) * 1024 + k];
    atomicAdd(&Uacc[k], acc);
}

__global__ __launch_bounds__(256) void k_h1(const float* __restrict__ Uacc,
                                            const float* __restrict__ b1,
                                            float* __restrict__ H1, float* __restrict__ D1) {
    int k = blockIdx.x * 256 + threadIdx.x;  // grid 4
    float h = tanhf(Uacc[k] + b1[k]);
    H1[k] = h;
    D1[k] = 1.f - h * h;
}

__global__ __launch_bounds__(256) void k_v_partial(const float* __restrict__ W2,
                                                   const float* __restrict__ H1,
                                                   float* __restrict__ Vacc) {
    int m = blockIdx.x * 256 + threadIdx.x;  // grid (4,16)
    int k0 = blockIdx.y * 64;
    __shared__ float hs[64];
    if (threadIdx.x < 64) hs[threadIdx.x] = H1[k0 + threadIdx.x];
    __syncthreads();
    float acc = 0.f;
#pragma unroll 8
    for (int k = 0; k < 64; ++k) acc += hs[k] * W2[(k0 + k) * 1024 + m];
    atomicAdd(&Vacc[m], acc);
}

__global__ __launch_bounds__(256) void k_h2(const float* __restrict__ Vacc,
                                            const float* __restrict__ b2,
                                            const float* __restrict__ W3,
                                            float* __restrict__ Svec, float* __restrict__ Cvec) {
    int m = blockIdx.x * 256 + threadIdx.x;  // grid 4
    float h = tanhf(Vacc[m] + b2[m]);
    float d2 = 1.f - h * h;
    float w3 = W3[m];
    Svec[m] = d2 * w3;
    Cvec[m] = -2.f * h * d2 * w3;
}

__global__ __launch_bounds__(256) void k_g(const float* __restrict__ W2,
                                           const float* __restrict__ Svec,
                                           const float* __restrict__ H1,
                                           const float* __restrict__ D1,
                                           float* __restrict__ Avec) {
    int k = blockIdx.x;  // grid 1024
    int t = threadIdx.x;
    float acc = 0.f;
#pragma unroll
    for (int m = t; m < 1024; m += 256) acc += W2[k * 1024 + m] * Svec[m];
    for (int o = 32; o; o >>= 1) acc += __shfl_down(acc, o);
    __shared__ float red[4];
    int lane = t & 63, w = t >> 6;
    if (lane == 0) red[w] = acc;
    __syncthreads();
    if (t == 0) Avec[k] = -2.f * H1[k] * D1[k] * (red[0] + red[1] + red[2] + red[3]);
}

// ---------- bf16 hi/lo prep ----------
// W1 rows 0..1023 -> Ah, Al
__global__ __launch_bounds__(256) void k_prep_a(const float* __restrict__ W1,
                                                u16* __restrict__ Ah, u16* __restrict__ Al) {
    int idx = (blockIdx.x * 256 + threadIdx.x) * 4;  // grid 1024 -> 1M floats
    float4 v = *(const float4*)(W1 + idx);
    u16 h0, l0, h1, l1, h2, l2, h3, l3;
    split2(v.x, h0, l0); split2(v.y, h1, l1); split2(v.z, h2, l2); split2(v.w, h3, l3);
    *(uint2*)&Ah[idx] = pack4(h0, h1, h2, h3);
    *(uint2*)&Al[idx] = pack4(l0, l1, l2, l3);
}

// W2 -> W2h/W2l (direct [k][m]) and WTh/WTl (transposed+scaled: WT[m][k]=d1[k]*W2[k][m])
__global__ __launch_bounds__(256) void k_prep_w2(const float* __restrict__ W2,
                                                 const float* __restrict__ D1,
                                                 u16* __restrict__ W2h, u16* __restrict__ W2l,
                                                 u16* __restrict__ WTh, u16* __restrict__ WTl) {
    __shared__ float T[64][65];
    int k0 = blockIdx.y * 64, m0 = blockIdx.x * 64;
    int t = threadIdx.x;
    int rr = t >> 4, cc = (t & 15) * 4;
#pragma unroll
    for (int j = 0; j < 4; ++j) {
        int r = rr + j * 16;
        float4 v = *(const float4*)(W2 + (k0 + r) * 1024 + m0 + cc);
        T[r][cc + 0] = v.x; T[r][cc + 1] = v.y; T[r][cc + 2] = v.z; T[r][cc + 3] = v.w;
        u16 h0, l0, h1, l1, h2, l2, h3, l3;
        split2(v.x, h0, l0); split2(v.y, h1, l1); split2(v.z, h2, l2); split2(v.w, h3, l3);
        *(uint2*)&W2h[(k0 + r) * 1024 + m0 + cc] = pack4(h0, h1, h2, h3);
        *(uint2*)&W2l[(k0 + r) * 1024 + m0 + cc] = pack4(l0, l1, l2, l3);
    }
    __syncthreads();
#pragma unroll
    for (int j = 0; j < 4; ++j) {
        int mrow = rr + j * 16;
        float f0 = T[cc + 0][mrow] * D1[k0 + cc + 0];
        float f1 = T[cc + 1][mrow] * D1[k0 + cc + 1];
        float f2 = T[cc + 2][mrow] * D1[k0 + cc + 2];
        float f3 = T[cc + 3][mrow] * D1[k0 + cc + 3];
        u16 h0, l0, h1, l1, h2, l2, h3, l3;
        split2(f0, h0, l0); split2(f1, h1, l1); split2(f2, h2, l2); split2(f3, h3, l3);
        *(uint2*)&WTh[(m0 + mrow) * 1024 + k0 + cc] = pack4(h0, h1, h2, h3);
        *(uint2*)&WTl[(m0 + mrow) * 1024 + k0 + cc] = pack4(l0, l1, l2, l3);
    }
}

// ---------- MFMA GEMMs ----------
// S[i,m] = Cvec[m] * sum_k W1[i,k]*d1[k]*W2[k,m]  -> Sh/Sl (bf16 split)
// A = Ah/Al [i][k], B = WTh/WTl [m][k]. Tile 64x64, BK=32, 4 waves in 2x2.
#define LDSTR 56
__global__ __launch_bounds__(256) void k_gemm1(const u16* __restrict__ Ah, const u16* __restrict__ Al,
                                               const u16* __restrict__ Bh, const u16* __restrict__ Bl,
                                               const float* __restrict__ Cvec,
                                               u16* __restrict__ Sh, u16* __restrict__ Sl) {
    __shared__ u16 As[2][64 * LDSTR];
    __shared__ u16 Bs[2][64 * LDSTR];
    int tid = threadIdx.x, lane = tid & 63, wv = tid >> 6;
    int wy = wv >> 1, wx = wv & 1;
    int i0 = blockIdx.y * 64, m0 = blockIdx.x * 64;
    int srow = tid >> 2, sseg = (tid & 3) * 8;
    int ldso = srow * LDSTR + sseg;
    const u16* ap_h = Ah + (i0 + srow) * 1024 + sseg;
    const u16* ap_l = Al + (i0 + srow) * 1024 + sseg;
    const u16* bp_h = Bh + (m0 + srow) * 1024 + sseg;
    const u16* bp_l = Bl + (m0 + srow) * 1024 + sseg;
    int tx = lane & 15, qy = lane >> 4;
    int ra0 = (wy * 32 + tx) * LDSTR + qy * 8;
    int ra1 = (wy * 32 + 16 + tx) * LDSTR + qy * 8;
    int rb0 = (wx * 32 + tx) * LDSTR + qy * 8;
    int rb1 = (wx * 32 + 16 + tx) * LDSTR + qy * 8;
    f32x4 acc[2][2];
#pragma unroll
    for (int a = 0; a < 2; ++a)
#pragma unroll
        for (int b = 0; b < 2; ++b) acc[a][b] = (f32x4){0.f, 0.f, 0.f, 0.f};

    for (int k0 = 0; k0 < 1024; k0 += 32) {
        uint4 va_h = *(const uint4*)(ap_h + k0);
        uint4 va_l = *(const uint4*)(ap_l + k0);
        uint4 vb_h = *(const uint4*)(bp_h + k0);
        uint4 vb_l = *(const uint4*)(bp_l + k0);
        __syncthreads();
        *(uint4*)&As[0][ldso] = va_h;
        *(uint4*)&As[1][ldso] = va_l;
        *(uint4*)&Bs[0][ldso] = vb_h;
        *(uint4*)&Bs[1][ldso] = vb_l;
        __syncthreads();
        bf16x8 aH[2], aL[2], bH[2], bL[2];
        aH[0] = *(const bf16x8*)&As[0][ra0]; aH[1] = *(const bf16x8*)&As[0][ra1];
        aL[0] = *(const bf16x8*)&As[1][ra0]; aL[1] = *(const bf16x8*)&As[1][ra1];
        bH[0] = *(const bf16x8*)&Bs[0][rb0]; bH[1] = *(const bf16x8*)&Bs[0][rb1];
        bL[0] = *(const bf16x8*)&Bs[1][rb0]; bL[1] = *(const bf16x8*)&Bs[1][rb1];
#pragma unroll
        for (int si = 0; si < 2; ++si)
#pragma unroll
            for (int sj = 0; sj < 2; ++sj) {
                acc[si][sj] = mfma16(aH[si], bH[sj], acc[si][sj]);
                acc[si][sj] = mfma16(aH[si], bL[sj], acc[si][sj]);
                acc[si][sj] = mfma16(aL[si], bH[sj], acc[si][sj]);
            }
    }
#pragma unroll
    for (int sj = 0; sj < 2; ++sj) {
        int m = m0 + wx * 32 + sj * 16 + tx;
        float cm = Cvec[m];
#pragma unroll
        for (int si = 0; si < 2; ++si) {
            int ib = i0 + wy * 32 + si * 16 + qy * 4;
#pragma unroll
            for (int r = 0; r < 4; ++r) {
                float v = acc[si][sj][r] * cm;
                u16 h, l;
                split2(v, h, l);
                Sh[(ib + r) * 1024 + m] = h;
                Sl[(ib + r) * 1024 + m] = l;
            }
        }
    }
}

// Wm[i,k] = sum_m S[i,m]*W2[k,m]; fused epilogue:
// DR = Avec[k]*W1[i,k] + D1[k]*Wm; out[i] += sum_k W1[2048+i,k]*DR; out[1024+i] -= sum_k W1[1024+i,k]*DR
__global__ __launch_bounds__(256) void k_gemm2(const u16* __restrict__ Sh, const u16* __restrict__ Sl,
                                               const u16* __restrict__ W2h, const u16* __restrict__ W2l,
                                               const float* __restrict__ W1,
                                               const float* __restrict__ D1,
                                               const float* __restrict__ Avec,
                                               float* __restrict__ out) {
    __shared__ u16 As[2][64 * LDSTR];
    __shared__ u16 Bs[2][64 * LDSTR];
    int tid = threadIdx.x, lane = tid & 63, wv = tid >> 6;
    int wy = wv >> 1, wx = wv & 1;
    int i0 = blockIdx.y * 64, k0g = blockIdx.x * 64;
    int srow = tid >> 2, sseg = (tid & 3) * 8;
    int ldso = srow * LDSTR + sseg;
    const u16* ap_h = Sh + (i0 + srow) * 1024 + sseg;
    const u16* ap_l = Sl + (i0 + srow) * 1024 + sseg;
    const u16* bp_h = W2h + (k0g + srow) * 1024 + sseg;
    const u16* bp_l = W2l + (k0g + srow) * 1024 + sseg;
    int tx = lane & 15, qy = lane >> 4;
    int ra0 = (wy * 32 + tx) * LDSTR + qy * 8;
    int ra1 = (wy * 32 + 16 + tx) * LDSTR + qy * 8;
    int rb0 = (wx * 32 + tx) * LDSTR + qy * 8;
    int rb1 = (wx * 32 + 16 + tx) * LDSTR + qy * 8;
    f32x4 acc[2][2];
#pragma unroll
    for (int a = 0; a < 2; ++a)
#pragma unroll
        for (int b = 0; b < 2; ++b) acc[a][b] = (f32x4){0.f, 0.f, 0.f, 0.f};

    for (int m0 = 0; m0 < 1024; m0 += 32) {
        uint4 va_h = *(const uint4*)(ap_h + m0);
        uint4 va_l = *(const uint4*)(ap_l + m0);
        uint4 vb_h = *(const uint4*)(bp_h + m0);
        uint4 vb_l = *(const uint4*)(bp_l + m0);
        __syncthreads();
        *(uint4*)&As[0][ldso] = va_h;
        *(uint4*)&As[1][ldso] = va_l;
        *(uint4*)&Bs[0][ldso] = vb_h;
        *(uint4*)&Bs[1][ldso] = vb_l;
        __syncthreads();
        bf16x8 aH[2], aL[2], bH[2], bL[2];
        aH[0] = *(const bf16x8*)&As[0][ra0]; aH[1] = *(const bf16x8*)&As[0][ra1];
        aL[0] = *(const bf16x8*)&As[1][ra0]; aL[1] = *(const bf16x8*)&As[1][ra1];
        bH[0] = *(const bf16x8*)&Bs[0][rb0]; bH[1] = *(const bf16x8*)&Bs[0][rb1];
        bL[0] = *(const bf16x8*)&Bs[1][rb0]; bL[1] = *(const bf16x8*)&Bs[1][rb1];
#pragma unroll
        for (int si = 0; si < 2; ++si)
#pragma unroll
            for (int sj = 0; sj < 2; ++sj) {
                acc[si][sj] = mfma16(aH[si], bH[sj], acc[si][sj]);
                acc[si][sj] = mfma16(aH[si], bL[sj], acc[si][sj]);
                acc[si][sj] = mfma16(aL[si], bH[sj], acc[si][sj]);
            }
    }
    // fused epilogue
    int kk[2];
    float d1v[2], avv[2];
#pragma unroll
    for (int sj = 0; sj < 2; ++sj) {
        kk[sj] = k0g + wx * 32 + sj * 16 + tx;
        d1v[sj] = D1[kk[sj]];
        avv[sj] = Avec[kk[sj]];
    }
#pragma unroll
    for (int si = 0; si < 2; ++si) {
        int ib = i0 + wy * 32 + si * 16 + qy * 4;
#pragma unroll
        for (int r = 0; r < 4; ++r) {
            int i = ib + r;
            float pq = 0.f, pp = 0.f;
#pragma unroll
            for (int sj = 0; sj < 2; ++sj) {
                int k = kk[sj];
                float dr = avv[sj] * W1[i * 1024 + k] + d1v[sj] * acc[si][sj][r];
                pq += W1[(1024 + i) * 1024 + k] * dr;
                pp += W1[(2048 + i) * 1024 + k] * dr;
            }
            for (int o = 1; o < 16; o <<= 1) {
                pq += __shfl_xor(pq, o);
                pp += __shfl_xor(pp, o);
            }
            if (tx == 0) {
                atomicAdd(&out[i], pp);
                atomicAdd(&out[1024 + i], -pq);
            }
        }
    }
}

extern "C" void kernel_launch(void* const* d_in, const int* in_sizes, int n_in,
                              void* d_out, int out_size, void* d_ws, size_t ws_size,
                              hipStream_t stream) {
    const float* x = (const float*)d_in[0];
    const float* q = (const float*)d_in[1];
    const float* p = (const float*)d_in[2];
    const float* W1 = (const float*)d_in[3];
    const float* b1 = (const float*)d_in[4];
    const float* W2 = (const float*)d_in[5];
    const float* b2 = (const float*)d_in[6];
    const float* W3 = (const float*)d_in[7];
    float* out = (float*)d_out;
    float* ws = (float*)d_ws;
    float* H1 = ws, *D1 = ws + 1024, *Svec = ws + 2048, *Cvec = ws + 3072;
    float* Avec = ws + 4096, *Z = ws + 5120, *Uacc = ws + 8192;  // Vacc = Uacc+1024 (contiguous)
    u16* u0 = (u16*)(ws + 16384);
    u16* Ah = u0;
    u16* Al = u0 + 1048576;
    u16* WTh = u0 + 2097152;
    u16* WTl = u0 + 3145728;
    u16* W2h = u0 + 4194304;
    u16* W2l = u0 + 5242880;
    u16* Sh = u0 + 6291456;
    u16* Sl = u0 + 7340032;

    k_init<<<12, 256, 0, stream>>>(x, q, p, Z, out, Uacc);
    k_prep_a<<<1024, 256, 0, stream>>>(W1, Ah, Al);
    k_u_partial<<<dim3(4, 48), 256, 0, stream>>>(W1, Z, Uacc);
    k_h1<<<4, 256, 0, stream>>>(Uacc, b1, H1, D1);
    k_prep_w2<<<dim3(16, 16), 256, 0, stream>>>(W2, D1, W2h, W2l, WTh, WTl);
    k_v_partial<<<dim3(4, 16), 256, 0, stream>>>(W2, H1, Uacc + 1024);
    k_h2<<<4, 256, 0, stream>>>(Uacc + 1024, b2, W3, Svec, Cvec);
    k_g<<<1024, 256, 0, stream>>>(W2, Svec, H1, D1, Avec);
    k_gemm1<<<dim3(16, 16), 256, 0, stream>>>(Ah, Al, WTh, WTl, Cvec, Sh, Sl);
    k_gemm2<<<dim3(16, 16), 256, 0, stream>>>(Sh, Sl, W2h, W2l, W1, D1, Avec, out);
}